// Round 4
// baseline (98.832 us; speedup 1.0000x reference)
//
#include <hip/hip_runtime.h>
#include <stdint.h>

#define NN 8192
#define NE 8192
#define DIM 256
#define NW 128   // 64-bit words per adjacency row (8192 bits)
#define HCAP 64  // max common neighbors; worst case i==j -> deg_max ~55
#define TE 16    // edges per block (fused)

typedef short bf16x8 __attribute__((ext_vector_type(8)));
typedef float f32x4 __attribute__((ext_vector_type(4)));

__device__ __forceinline__ unsigned short f2bf(float f) {
  uint32_t u = __builtin_bit_cast(uint32_t, f);
  u += 0x7fffu + ((u >> 16) & 1u);   // round-to-nearest-even
  return (unsigned short)(u >> 16);
}
__device__ __forceinline__ float bf2f(unsigned short h) {
  uint32_t u = ((uint32_t)h) << 16;
  return __builtin_bit_cast(float, u);
}

// ============ prep: weight transpose (blocks 0..1535) + adj pack (rest) ====
// Pack bit layout: task t covers row r = t>>5, segment s = t&31 (256 cols).
// Lane l loads float4 at cols s*256 + 4l .. 4l+3. ballot(component q) ->
// word bits[r*128 + s*4 + q], bit l  <->  col = s*256 + 4*l + q.
__global__ __launch_bounds__(256) void prep_kernel(
    const float* __restrict__ adj,
    const float* __restrict__ W1c, const float* __restrict__ W2c,
    const float* __restrict__ W1j, const float* __restrict__ W2j,
    const float* __restrict__ Wl1, const float* __restrict__ Wl2,
    unsigned short* __restrict__ Wt,
    unsigned long long* __restrict__ bits) {
  const int blk = blockIdx.x;
  if (blk < 1536) {
    // Wt[w][n][k] = W[w][k][n], bf16
    const float* Ws[6] = {W1c, W2c, W1j, W2j, Wl1, Wl2};
    const int w = blk >> 8;
    const int n = blk & 255;
    const int k = threadIdx.x;
    Wt[w * 65536 + n * DIM + k] = f2bf(Ws[w][k * DIM + n]);
  } else {
    const float4* __restrict__ adjv = (const float4*)adj;
    const int lane = threadIdx.x & 63;
    const int wv = (blk - 1536) * 4 + (threadIdx.x >> 6);
    const int nwv = 4096 * 4;
    const int total = NN * 32;  // float4-tasks
    for (int t = 4 * wv; t < total; t += 4 * nwv) {
      float4 v0 = adjv[(size_t)((t + 0) >> 5) * 2048 + ((t + 0) & 31) * 64 + lane];
      float4 v1 = adjv[(size_t)((t + 1) >> 5) * 2048 + ((t + 1) & 31) * 64 + lane];
      float4 v2 = adjv[(size_t)((t + 2) >> 5) * 2048 + ((t + 2) & 31) * 64 + lane];
      float4 v3 = adjv[(size_t)((t + 3) >> 5) * 2048 + ((t + 3) & 31) * 64 + lane];
      unsigned long long m00 = __ballot(v0.x != 0.0f);
      unsigned long long m01 = __ballot(v0.y != 0.0f);
      unsigned long long m02 = __ballot(v0.z != 0.0f);
      unsigned long long m03 = __ballot(v0.w != 0.0f);
      unsigned long long m10 = __ballot(v1.x != 0.0f);
      unsigned long long m11 = __ballot(v1.y != 0.0f);
      unsigned long long m12 = __ballot(v1.z != 0.0f);
      unsigned long long m13 = __ballot(v1.w != 0.0f);
      unsigned long long m20 = __ballot(v2.x != 0.0f);
      unsigned long long m21 = __ballot(v2.y != 0.0f);
      unsigned long long m22 = __ballot(v2.z != 0.0f);
      unsigned long long m23 = __ballot(v2.w != 0.0f);
      unsigned long long m30 = __ballot(v3.x != 0.0f);
      unsigned long long m31 = __ballot(v3.y != 0.0f);
      unsigned long long m32 = __ballot(v3.z != 0.0f);
      unsigned long long m33 = __ballot(v3.w != 0.0f);
      if (lane == 0) {
        // tasks t..t+3 are within one row (t%4==0, (t&31)<=28): 16 contiguous words
        unsigned long long* p = bits + (size_t)(t >> 5) * NW + (t & 31) * 4;
        p[0]  = m00; p[1]  = m01; p[2]  = m02; p[3]  = m03;
        p[4]  = m10; p[5]  = m11; p[6]  = m12; p[7]  = m13;
        p[8]  = m20; p[9]  = m21; p[10] = m22; p[11] = m23;
        p[12] = m30; p[13] = m31; p[14] = m32; p[15] = m33;
      }
    }
  }
}

// ================= fused: CN intersect + xixj + 6-GEMM chain + GEMV ========
// Block: 512 threads = 8 waves, TE=16 edges. mfma_f32_16x16x32_bf16.
// Each wave owns 32 output cols (2 n-tiles), single 16-row m-tile.
// A-frag: row = lane&15, k = (lane>>4)*8 + j
// B-frag: col = lane&15, k = (lane>>4)*8 + j  -> Wt[col][k] contiguous
// C/D:    col = lane&15, row = (lane>>4)*4 + reg   (m89-verified)

#define LDP 264  // 256 + 8 bf16 pad (row stride 528 B, 2-way bank alias = free)

__device__ __forceinline__ void do_gemm16(const unsigned short (*src)[LDP],
                                          const unsigned short* __restrict__ Wt,
                                          f32x4 acc[2], int lane, int wave) {
  const int lr = lane & 15;
  const int kl = (lane >> 4) * 8;
  const int n0 = wave * 32;
#pragma unroll
  for (int kk = 0; kk < 8; ++kk) {
    const int k0 = kk * 32 + kl;
    bf16x8 a0 = *(const bf16x8*)(&src[lr][k0]);
    bf16x8 b0 = *(const bf16x8*)(Wt + (size_t)(n0 + lr) * DIM + k0);
    bf16x8 b1 = *(const bf16x8*)(Wt + (size_t)(n0 + 16 + lr) * DIM + k0);
    acc[0] = __builtin_amdgcn_mfma_f32_16x16x32_bf16(a0, b0, acc[0], 0, 0, 0);
    acc[1] = __builtin_amdgcn_mfma_f32_16x16x32_bf16(a0, b1, acc[1], 0, 0, 0);
  }
}

__device__ __forceinline__ void epilogue16(f32x4 acc[2],
                                           const float* __restrict__ bias,
                                           bool relu, unsigned short (*dst)[LDP],
                                           int lane, int wave) {
  const int lc = lane & 15;
  const int rg = (lane >> 4) * 4;
#pragma unroll
  for (int n = 0; n < 2; ++n) {
    const int col = wave * 32 + n * 16 + lc;
    const float bb = bias[col];
#pragma unroll
    for (int q = 0; q < 4; ++q) {
      float v = acc[n][q] + bb;
      if (relu) v = fmaxf(v, 0.f);
      dst[rg + q][col] = f2bf(v);
    }
  }
}

__global__ __launch_bounds__(512) void fused_kernel(
    const float* __restrict__ x,
    const unsigned long long* __restrict__ bits,
    const int* __restrict__ tar,
    const unsigned short* __restrict__ Wt,
    const float* __restrict__ b1c, const float* __restrict__ b2c,
    const float* __restrict__ b1j, const float* __restrict__ b2j,
    const float* __restrict__ bl1, const float* __restrict__ bl2,
    const float* __restrict__ Wout, const float* __restrict__ bout,
    float* __restrict__ out) {
  __shared__ unsigned short lA[TE][LDP];  // xcn -> U2 -> final h
  __shared__ unsigned short lB[TE][LDP];  // U1 -> h
  __shared__ unsigned short lC[TE][LDP];  // xixj -> h2
  __shared__ int hits[TE][HCAP];
  __shared__ int nh[TE];
  __shared__ int ii[TE], jj[TE];

  const int tid = threadIdx.x;
  const int lane = tid & 63;
  const int wave = tid >> 6;
  const int e0 = blockIdx.x * TE;

  if (tid < TE) {
    ii[tid] = tar[e0 + tid];
    jj[tid] = tar[NE + e0 + tid];
    nh[tid] = 0;
  }
  __syncthreads();

  // ---- phase X: xixj (independent of bits) — issue loads early ----
  {
    const int col = tid & 255;
    const int sub = tid >> 8;  // 0/1 -> edges sub*8 .. sub*8+7
    float vi[8], vj[8];
#pragma unroll
    for (int p = 0; p < 8; ++p) {
      const int e = sub * 8 + p;
      vi[p] = x[(size_t)ii[e] * DIM + col];
      vj[p] = x[(size_t)jj[e] * DIM + col];
    }
#pragma unroll
    for (int p = 0; p < 8; ++p)
      lC[sub * 8 + p][col] = f2bf(vi[p] * vj[p]);
  }

  // ---- phase A: bitmask intersection (32 threads/edge, 4 words each) ----
  {
    const int e = tid >> 5;
    const int t32 = tid & 31;
    const unsigned long long* bi = bits + (size_t)ii[e] * NW + t32 * 4;
    const unsigned long long* bj = bits + (size_t)jj[e] * NW + t32 * 4;
#pragma unroll
    for (int q = 0; q < 4; ++q) {
      unsigned long long m = bi[q] & bj[q];
      while (m) {
        int b = __builtin_ctzll(m);
        m &= m - 1;
        int idx = atomicAdd(&nh[e], 1);
        // decoded node id: col = t32*256 + 4*b + q
        if (idx < HCAP) hits[e][idx] = (t32 << 8) + (b << 2) + q;
      }
    }
  }
  __syncthreads();

  // ---- phase B: xcn gathers -> lA ----
  {
    const int col = tid & 255;
    const int sub = tid >> 8;
#pragma unroll
    for (int p = 0; p < 8; ++p) {
      const int e = sub * 8 + p;
      const int n = nh[e] < HCAP ? nh[e] : HCAP;
      float xc = 0.f;
      for (int h = 0; h < n; ++h)
        xc += x[(size_t)hits[e][h] * DIM + col];
      lA[e][col] = f2bf(xc);
    }
  }
  __syncthreads();

  f32x4 acc[2], pAcc[2];
  const f32x4 z4 = {0.f, 0.f, 0.f, 0.f};

  // ---- S1: U1 = relu(xcn @ W1c + b1c) -> lB ----
  acc[0] = z4; acc[1] = z4;
  do_gemm16(lA, Wt + 0 * 65536, acc, lane, wave);
  epilogue16(acc, b1c, true, lB, lane, wave);
  __syncthreads();

  // ---- S2: pAcc = U1 @ W2c ;  S3: U2 = relu(xixj @ W1j + b1j) -> lA ----
  pAcc[0] = z4; pAcc[1] = z4;
  do_gemm16(lB, Wt + 1 * 65536, pAcc, lane, wave);
  acc[0] = z4; acc[1] = z4;
  do_gemm16(lC, Wt + 2 * 65536, acc, lane, wave);
  epilogue16(acc, b1j, true, lA, lane, wave);
  __syncthreads();

  // ---- S4: pAcc += U2 @ W2j ; h = pAcc + b2c + b2j -> lB (no relu) ----
  do_gemm16(lA, Wt + 3 * 65536, pAcc, lane, wave);
  {
    const int lc = lane & 15;
    const int rg = (lane >> 4) * 4;
#pragma unroll
    for (int n = 0; n < 2; ++n) {
      const int col = wave * 32 + n * 16 + lc;
      const float bb = b2c[col] + b2j[col];
#pragma unroll
      for (int q = 0; q < 4; ++q)
        lB[rg + q][col] = f2bf(pAcc[n][q] + bb);
    }
  }
  __syncthreads();

  // ---- S5: h2 = relu(h @ Wl1 + bl1) -> lC ----
  acc[0] = z4; acc[1] = z4;
  do_gemm16(lB, Wt + 4 * 65536, acc, lane, wave);
  epilogue16(acc, bl1, true, lC, lane, wave);
  __syncthreads();

  // ---- S6: h3 = relu(h2 @ Wl2 + bl2) -> lA ----
  acc[0] = z4; acc[1] = z4;
  do_gemm16(lC, Wt + 5 * 65536, acc, lane, wave);
  epilogue16(acc, bl2, true, lA, lane, wave);
  __syncthreads();

  // ---- GEMV: out = h3 @ Wout + bout (32 threads per edge, 8 cols each) ----
  const int el = tid >> 5;
  const int part = tid & 31;
  float s = 0.f;
#pragma unroll
  for (int q = 0; q < 8; ++q) {
    const int c = part * 8 + q;
    s += bf2f(lA[el][c]) * Wout[c];
  }
#pragma unroll
  for (int o = 16; o; o >>= 1) s += __shfl_xor(s, o);
  if (part == 0) out[e0 + el] = s + bout[0];
}

extern "C" void kernel_launch(void* const* d_in, const int* in_sizes, int n_in,
                              void* d_out, int out_size, void* d_ws, size_t ws_size,
                              hipStream_t stream) {
  const float* x    = (const float*)d_in[0];
  const float* adj  = (const float*)d_in[1];
  const int*   tar  = (const int*)d_in[2];
  const float* W1c  = (const float*)d_in[3];
  const float* b1c  = (const float*)d_in[4];
  const float* W2c  = (const float*)d_in[5];
  const float* b2c  = (const float*)d_in[6];
  const float* W1j  = (const float*)d_in[7];
  const float* b1j  = (const float*)d_in[8];
  const float* W2j  = (const float*)d_in[9];
  const float* b2j  = (const float*)d_in[10];
  const float* Wl1  = (const float*)d_in[11];
  const float* bl1  = (const float*)d_in[12];
  const float* Wl2  = (const float*)d_in[13];
  const float* bl2  = (const float*)d_in[14];
  const float* Wout = (const float*)d_in[15];
  const float* bout = (const float*)d_in[16];

  char* ws = (char*)d_ws;
  unsigned short*     Wt   = (unsigned short*)(ws);                  // 768 KB
  unsigned long long* bits = (unsigned long long*)(ws + (1u << 20)); // 8 MB

  prep_kernel<<<1536 + 4096, 256, 0, stream>>>(adj, W1c, W2c, W1j, W2j, Wl1,
                                               Wl2, Wt, bits);

  fused_kernel<<<NE / TE, 512, 0, stream>>>(x, bits, tar, Wt, b1c, b2c, b1j,
                                            b2j, bl1, bl2, Wout, bout,
                                            (float*)d_out);
}

// Round 5
// 81.220 us; speedup vs baseline: 1.2168x; 1.2168x over previous
//
#include <hip/hip_runtime.h>
#include <stdint.h>

#define NN 8192
#define NE 8192
#define DIM 256
#define NW 128   // 64-bit words per adjacency row (8192 bits)
#define HCAP 64  // max common neighbors; worst case i==j -> deg_max ~55
#define TE 32    // edges per block (fused)

typedef short bf16x8 __attribute__((ext_vector_type(8)));
typedef float f32x4 __attribute__((ext_vector_type(4)));

__device__ __forceinline__ unsigned short f2bf(float f) {
  uint32_t u = __builtin_bit_cast(uint32_t, f);
  u += 0x7fffu + ((u >> 16) & 1u);   // round-to-nearest-even
  return (unsigned short)(u >> 16);
}
__device__ __forceinline__ float bf2f(unsigned short h) {
  uint32_t u = ((uint32_t)h) << 16;
  return __builtin_bit_cast(float, u);
}

// ============ prep: weight transpose (blocks 0..1535) + adj pack (rest) ====
// Pack bit layout: task t covers row r = t>>5, segment s = t&31 (256 cols).
// Lane l loads float4 at cols s*256 + 4l .. 4l+3. ballot(component q) ->
// word bits[r*128 + s*4 + q], bit l  <->  col = s*256 + 4*l + q.
__global__ __launch_bounds__(256) void prep_kernel(
    const float* __restrict__ adj,
    const float* __restrict__ W1c, const float* __restrict__ W2c,
    const float* __restrict__ W1j, const float* __restrict__ W2j,
    const float* __restrict__ Wl1, const float* __restrict__ Wl2,
    unsigned short* __restrict__ Wt,
    unsigned long long* __restrict__ bits) {
  const int blk = blockIdx.x;
  if (blk < 1536) {
    // Wt[w][n][k] = W[w][k][n], bf16
    const float* Ws[6] = {W1c, W2c, W1j, W2j, Wl1, Wl2};
    const int w = blk >> 8;
    const int n = blk & 255;
    const int k = threadIdx.x;
    Wt[w * 65536 + n * DIM + k] = f2bf(Ws[w][k * DIM + n]);
  } else {
    const float4* __restrict__ adjv = (const float4*)adj;
    const int lane = threadIdx.x & 63;
    const int wv = (blk - 1536) * 4 + (threadIdx.x >> 6);
    const int nwv = 4096 * 4;
    const int total = NN * 32;  // float4-tasks
    for (int t = 2 * wv; t < total; t += 2 * nwv) {
      const int t1 = t + 1;
      float4 v0 = adjv[(size_t)(t >> 5) * 2048 + (t & 31) * 64 + lane];
      float4 v1 = adjv[(size_t)(t1 >> 5) * 2048 + (t1 & 31) * 64 + lane];
      unsigned long long m0 = __ballot(v0.x != 0.0f);
      unsigned long long m1 = __ballot(v0.y != 0.0f);
      unsigned long long m2 = __ballot(v0.z != 0.0f);
      unsigned long long m3 = __ballot(v0.w != 0.0f);
      unsigned long long n0 = __ballot(v1.x != 0.0f);
      unsigned long long n1 = __ballot(v1.y != 0.0f);
      unsigned long long n2 = __ballot(v1.z != 0.0f);
      unsigned long long n3 = __ballot(v1.w != 0.0f);
      if (lane == 0) {
        unsigned long long* p0 = bits + (size_t)(t >> 5) * NW + (t & 31) * 4;
        unsigned long long* p1 = bits + (size_t)(t1 >> 5) * NW + (t1 & 31) * 4;
        p0[0] = m0; p0[1] = m1; p0[2] = m2; p0[3] = m3;
        p1[0] = n0; p1[1] = n1; p1[2] = n2; p1[3] = n3;
      }
    }
  }
}

// ================= fused: CN intersect + xixj + 6-GEMM chain + GEMV ========
// Block: 512 threads = 8 waves, TE=32 edges. mfma_f32_16x16x32_bf16.
// Each wave owns 32 output cols (2 n-tiles) x 2 m-tiles of 16 rows.
// A-frag: row = lane&15, k = (lane>>4)*8 + j
// B-frag: col = lane&15, k = (lane>>4)*8 + j  (register-resident, prefetched)
// C/D:    col = lane&15, row = (lane>>4)*4 + reg   (m89-verified)

#define LDP 264  // 256 + 8 bf16 pad (row stride 528 B, 2-way bank alias = free)

__device__ __forceinline__ void load_w(const unsigned short* __restrict__ Wt,
                                       bf16x8 w[2][8], int lane, int wave) {
  const int lr = lane & 15;
  const int kl = (lane >> 4) * 8;
  const int n0 = wave * 32;
#pragma unroll
  for (int kk = 0; kk < 8; ++kk) {
    const int k0 = kk * 32 + kl;
    w[0][kk] = *(const bf16x8*)(Wt + (size_t)(n0 + lr) * DIM + k0);
    w[1][kk] = *(const bf16x8*)(Wt + (size_t)(n0 + 16 + lr) * DIM + k0);
  }
}

__device__ __forceinline__ void gemm_reg(const unsigned short (*src)[LDP],
                                         const bf16x8 w[2][8],
                                         f32x4 acc[2][2], int lane) {
  const int lr = lane & 15;
  const int kl = (lane >> 4) * 8;
#pragma unroll
  for (int kk = 0; kk < 8; ++kk) {
    const int k0 = kk * 32 + kl;
    bf16x8 a0 = *(const bf16x8*)(&src[lr][k0]);
    bf16x8 a1 = *(const bf16x8*)(&src[16 + lr][k0]);
    acc[0][0] = __builtin_amdgcn_mfma_f32_16x16x32_bf16(a0, w[0][kk], acc[0][0], 0, 0, 0);
    acc[0][1] = __builtin_amdgcn_mfma_f32_16x16x32_bf16(a0, w[1][kk], acc[0][1], 0, 0, 0);
    acc[1][0] = __builtin_amdgcn_mfma_f32_16x16x32_bf16(a1, w[0][kk], acc[1][0], 0, 0, 0);
    acc[1][1] = __builtin_amdgcn_mfma_f32_16x16x32_bf16(a1, w[1][kk], acc[1][1], 0, 0, 0);
  }
}

__device__ __forceinline__ void zero22(f32x4 a[2][2]) {
#pragma unroll
  for (int m = 0; m < 2; ++m)
#pragma unroll
    for (int n = 0; n < 2; ++n) {
      f32x4 z = {0.f, 0.f, 0.f, 0.f};
      a[m][n] = z;
    }
}

__device__ __forceinline__ void epilogue32(f32x4 acc[2][2], float bb0, float bb1,
                                           bool relu, unsigned short (*dst)[LDP],
                                           int lane, int wave) {
  const int lc = lane & 15;
  const int rg = (lane >> 4) * 4;
#pragma unroll
  for (int n = 0; n < 2; ++n) {
    const int col = wave * 32 + n * 16 + lc;
    const float bb = n ? bb1 : bb0;
#pragma unroll
    for (int m = 0; m < 2; ++m)
#pragma unroll
      for (int q = 0; q < 4; ++q) {
        float v = acc[m][n][q] + bb;
        if (relu) v = fmaxf(v, 0.f);
        dst[m * 16 + rg + q][col] = f2bf(v);
      }
  }
}

__global__ __launch_bounds__(512, 2) void fused_kernel(
    const float* __restrict__ x,
    const unsigned long long* __restrict__ bits,
    const int* __restrict__ tar,
    const unsigned short* __restrict__ Wt,
    const float* __restrict__ b1c, const float* __restrict__ b2c,
    const float* __restrict__ b1j, const float* __restrict__ b2j,
    const float* __restrict__ bl1, const float* __restrict__ bl2,
    const float* __restrict__ Wout, const float* __restrict__ bout,
    float* __restrict__ out) {
  __shared__ unsigned short lA[TE][LDP];  // xcn -> U2 -> h2
  __shared__ unsigned short lB[TE][LDP];  // U1 -> h -> h3
  __shared__ unsigned short lC[TE][LDP];  // xixj
  __shared__ int hits[TE][HCAP];
  __shared__ int nh[TE];

  const int tid = threadIdx.x;
  const int lane = tid & 63;
  const int wave = tid >> 6;
  const int e0 = blockIdx.x * TE;

  // ---- per-lane constant preloads (biases, Wout) ----
  const int lc = lane & 15;
  const int c0 = wave * 32 + lc;
  const int c1 = c0 + 16;
  const float vb1c0 = b1c[c0], vb1c1 = b1c[c1];
  const float vb1j0 = b1j[c0], vb1j1 = b1j[c1];
  const float vb20 = b2c[c0] + b2j[c0], vb21 = b2c[c1] + b2j[c1];
  const float vbl10 = bl1[c0], vbl11 = bl1[c1];
  const float vbl20 = bl2[c0], vbl21 = bl2[c1];
  const int gpart = tid & 15;  // GEMV: 16 threads/edge
  float wv[16];
#pragma unroll
  for (int q = 0; q < 16; ++q) wv[q] = Wout[gpart * 16 + q];
  const float vbout = bout[0];

  if (tid < TE) nh[tid] = 0;

  // ---- (a) bits words -> regs (16 thr/edge, 8 words each endpoint) ----
  const int e_a = tid >> 4;
  const int t16 = tid & 15;
  const int ia = tar[e0 + e_a];
  const int ja = tar[NE + e0 + e_a];
  unsigned long long bw_i[8], bw_j[8];
  {
    const unsigned long long* bi = bits + (size_t)ia * NW + t16 * 8;
    const unsigned long long* bj = bits + (size_t)ja * NW + t16 * 8;
#pragma unroll
    for (int q = 0; q < 8; ++q) { bw_i[q] = bi[q]; bw_j[q] = bj[q]; }
  }

  // ---- (b) xixj -> lC (independent; hides (a)'s latency) ----
  {
    const int col = tid & 255;
    const int sub = tid >> 8;  // 0/1 -> 16 edges each
    float vi[16], vj[16];
#pragma unroll
    for (int p = 0; p < 16; ++p) {
      const int e = sub * 16 + p;
      vi[p] = x[(size_t)tar[e0 + e] * DIM + col];
      vj[p] = x[(size_t)tar[NE + e0 + e] * DIM + col];
    }
#pragma unroll
    for (int p = 0; p < 16; ++p)
      lC[sub * 16 + p][col] = f2bf(vi[p] * vj[p]);
  }
  __syncthreads();  // nh zeroed; (a)/(b) loads drained

  // ---- (c) intersect (pure VALU + LDS atomics) ----
#pragma unroll
  for (int q = 0; q < 8; ++q) {
    unsigned long long m = bw_i[q] & bw_j[q];
    const int w = t16 * 8 + q;
    const int base = (w >> 2) << 8;
    const int qq = w & 3;
    while (m) {
      int b = __builtin_ctzll(m);
      m &= m - 1;
      int idx = atomicAdd(&nh[e_a], 1);
      if (idx < HCAP) hits[e_a][idx] = base + (b << 2) + qq;  // node id
    }
  }
  __syncthreads();

  // ---- prefetch S1/S2 weights; (B) xcn gathers -> lA ----
  bf16x8 wX[2][8], wY[2][8];
  load_w(Wt + 0 * 65536, wX, lane, wave);
  load_w(Wt + 1 * 65536, wY, lane, wave);
  {
    const int col = tid & 255;
    const int sub = tid >> 8;
#pragma unroll
    for (int p = 0; p < 16; ++p) {
      const int e = sub * 16 + p;
      const int n = nh[e] < HCAP ? nh[e] : HCAP;
      float xc = 0.f;
      for (int h = 0; h < n; ++h)
        xc += x[(size_t)hits[e][h] * DIM + col];
      lA[e][col] = f2bf(xc);
    }
  }
  __syncthreads();

  f32x4 acc[2][2], pAcc[2][2];

  // ---- S1: U1 = relu(xcn @ W1c + b1c) -> lB ; prefetch Wt2 -> wX ----
  zero22(acc);
  gemm_reg(lA, wX, acc, lane);
  load_w(Wt + 2 * 65536, wX, lane, wave);
  epilogue32(acc, vb1c0, vb1c1, true, lB, lane, wave);
  __syncthreads();

  // ---- S2: pAcc = U1 @ W2c (wY); S3: U2 = relu(xixj @ W1j) -> lA (wX) ----
  zero22(pAcc);
  gemm_reg(lB, wY, pAcc, lane);
  load_w(Wt + 3 * 65536, wY, lane, wave);  // prefetch W2j
  zero22(acc);
  gemm_reg(lC, wX, acc, lane);
  epilogue32(acc, vb1j0, vb1j1, true, lA, lane, wave);
  __syncthreads();

  // ---- S4: pAcc += U2 @ W2j (wY); h = pAcc + b2c+b2j -> lB (no relu) ----
  gemm_reg(lA, wY, pAcc, lane);
  load_w(Wt + 4 * 65536, wX, lane, wave);  // prefetch Wl1
  {
    const int rg = (lane >> 4) * 4;
#pragma unroll
    for (int n = 0; n < 2; ++n) {
      const int col = wave * 32 + n * 16 + lc;
      const float bb = n ? vb21 : vb20;
#pragma unroll
      for (int m = 0; m < 2; ++m)
#pragma unroll
        for (int q = 0; q < 4; ++q)
          lB[m * 16 + rg + q][col] = f2bf(pAcc[m][n][q] + bb);
    }
  }
  __syncthreads();

  // ---- S5: h2 = relu(h @ Wl1 + bl1) -> lA (wX) ; prefetch Wl2 -> wY ----
  zero22(acc);
  gemm_reg(lB, wX, acc, lane);
  load_w(Wt + 5 * 65536, wY, lane, wave);
  epilogue32(acc, vbl10, vbl11, true, lA, lane, wave);
  __syncthreads();

  // ---- S6: h3 = relu(h2 @ Wl2 + bl2) -> lB (wY) ----
  zero22(acc);
  gemm_reg(lA, wY, acc, lane);
  epilogue32(acc, vbl20, vbl21, true, lB, lane, wave);
  __syncthreads();

  // ---- GEMV: out = h3 @ Wout + bout (16 threads/edge, preloaded Wout) ----
  const int el = tid >> 4;
  float s = 0.f;
#pragma unroll
  for (int q = 0; q < 16; ++q)
    s += bf2f(lB[el][gpart * 16 + q]) * wv[q];
#pragma unroll
  for (int o = 8; o; o >>= 1) s += __shfl_xor(s, o);
  if (gpart == 0) out[e0 + el] = s + vbout;
}

extern "C" void kernel_launch(void* const* d_in, const int* in_sizes, int n_in,
                              void* d_out, int out_size, void* d_ws, size_t ws_size,
                              hipStream_t stream) {
  const float* x    = (const float*)d_in[0];
  const float* adj  = (const float*)d_in[1];
  const int*   tar  = (const int*)d_in[2];
  const float* W1c  = (const float*)d_in[3];
  const float* b1c  = (const float*)d_in[4];
  const float* W2c  = (const float*)d_in[5];
  const float* b2c  = (const float*)d_in[6];
  const float* W1j  = (const float*)d_in[7];
  const float* b1j  = (const float*)d_in[8];
  const float* W2j  = (const float*)d_in[9];
  const float* b2j  = (const float*)d_in[10];
  const float* Wl1  = (const float*)d_in[11];
  const float* bl1  = (const float*)d_in[12];
  const float* Wl2  = (const float*)d_in[13];
  const float* bl2  = (const float*)d_in[14];
  const float* Wout = (const float*)d_in[15];
  const float* bout = (const float*)d_in[16];

  char* ws = (char*)d_ws;
  unsigned short*     Wt   = (unsigned short*)(ws);                  // 768 KB
  unsigned long long* bits = (unsigned long long*)(ws + (1u << 20)); // 8 MB

  prep_kernel<<<1536 + 4096, 256, 0, stream>>>(adj, W1c, W2c, W1j, W2j, Wl1,
                                               Wl2, Wt, bits);

  fused_kernel<<<NE / TE, 512, 0, stream>>>(x, bits, tar, Wt, b1c, b2c, b1j,
                                            b2j, bl1, bl2, Wout, bout,
                                            (float*)d_out);
}